// Round 12
// baseline (69.322 us; speedup 1.0000x reference)
//
#include <hip/hip_runtime.h>
#include <hip/hip_bf16.h>

// Dense softmax attention (NO 1/sqrt(D) scale). B=4, L=2048, H=8, D=64,
// fp32 in/out, layout (B, L, H, D).
// Round 11: K32 PV via permlane half-swaps (kill half-rate K16 MFMAs).
//  - Rounds 7/9/10 all ~62-64us under different schedules -> not schedule-
//    bound. MFMA budget: K16 PV = 20 of 28 MFMA slots for half-rate MACs.
//  - S^T acc (q=ln, k=kg*16+lg*4+r) -> K32 B-operand (k=lg*8+j) via
//    cvt_pk x4 then permlane32_swap x2 + permlane16_swap x2 per ms:
//      PL32(A,C) -> t0={A0,A1,C0,C1}, t1={A2,A3,C2,C3}
//      PL16(t0,t1) -> {A0,A2,C0,C2}=u32[0], {A1,A3,C1,C3}=u32[2]
//      (B,D) likewise -> u32[1], u32[3]. Verified index-exact.
//  - PV: 4 dg + 1 lsum K32 bf16 MFMAs per ms (was 10 K16). V^T natural
//    layout again (b128 reads), paired-permutation deleted.
//  - Everything else = round 10 (passed, 0.03125): dbuf one-barrier
//    sandwich loop, named-scalar stage regs, f16 QK^T swapped mfma(K,Q),
//    log2e in Q, exp2, 4 qsub x 2 ks waves, XCD swizzle, k-split merge.

#define B_ 4
#define L_ 2048
#define H_ 8
#define D_ 64
#define RST_ 512               // floats between consecutive l (H_*D_)
#define QW_ 32
#define QB_ 128                // 4 q-subs * 32 rows
#define KT_ 64
#define NT_ (L_ / KT_)         // 32
#define RS_ 88                 // K/V LDS row stride, 2B units (176B)
#define OTS_ 68                // epilogue transpose row stride, f32
#define SCW_ 35                // merge scratch words/lane
#define LOG2E_ 1.44269504088896f

// smem: Kf0 0 | Kf1 11264 | Vt0 22528 | Vt1 33792 ; total 45056
//       epilogue overlay: Sc[4][64][SCW_] f32 (35840B); Ot[w<4] at w*8960
#define SMEM_BYTES 45056

typedef _Float16 f16x8 __attribute__((ext_vector_type(8)));
typedef __bf16   bf16x8 __attribute__((ext_vector_type(8)));
typedef float    f32x4 __attribute__((ext_vector_type(4)));
typedef unsigned u32x2 __attribute__((ext_vector_type(2)));

__device__ __forceinline__ unsigned pk_bf16(float a, float b) {
    const __bf16 x = (__bf16)a, y = (__bf16)b;
    return ((unsigned)__builtin_bit_cast(unsigned short, y) << 16) |
           (unsigned)__builtin_bit_cast(unsigned short, x);
}

// compute for one LITERAL ms value; reads kfr/vf/qf, updates o[ms], lsum[ms]
#define COMPUTE_MS(ms)                                                         \
    do {                                                                       \
        f32x4 st0 = (f32x4){0.f, 0.f, 0.f, 0.f};                               \
        f32x4 st1 = (f32x4){0.f, 0.f, 0.f, 0.f};                               \
        __builtin_amdgcn_s_setprio(1);                                         \
        st0 = __builtin_amdgcn_mfma_f32_16x16x32_f16(kfr[0][0], qf[ms][0], st0, 0, 0, 0); \
        st1 = __builtin_amdgcn_mfma_f32_16x16x32_f16(kfr[0][1], qf[ms][0], st1, 0, 0, 0); \
        st0 = __builtin_amdgcn_mfma_f32_16x16x32_f16(kfr[1][0], qf[ms][1], st0, 0, 0, 0); \
        st1 = __builtin_amdgcn_mfma_f32_16x16x32_f16(kfr[1][1], qf[ms][1], st1, 0, 0, 0); \
        __builtin_amdgcn_s_setprio(0);                                         \
        const float e0 = __builtin_amdgcn_exp2f(st0[0]);                       \
        const float e1 = __builtin_amdgcn_exp2f(st0[1]);                       \
        const float e2 = __builtin_amdgcn_exp2f(st0[2]);                       \
        const float e3 = __builtin_amdgcn_exp2f(st0[3]);                       \
        const float e4 = __builtin_amdgcn_exp2f(st1[0]);                       \
        const float e5 = __builtin_amdgcn_exp2f(st1[1]);                       \
        const float e6 = __builtin_amdgcn_exp2f(st1[2]);                       \
        const float e7 = __builtin_amdgcn_exp2f(st1[3]);                       \
        const unsigned pA = pk_bf16(e0, e1);                                   \
        const unsigned pB = pk_bf16(e2, e3);                                   \
        const unsigned pC = pk_bf16(e4, e5);                                   \
        const unsigned pD = pk_bf16(e6, e7);                                   \
        const u32x2 tac = __builtin_amdgcn_permlane32_swap(pA, pC, false, false); \
        const u32x2 uac = __builtin_amdgcn_permlane16_swap(tac[0], tac[1], false, false); \
        const u32x2 tbd = __builtin_amdgcn_permlane32_swap(pB, pD, false, false); \
        const u32x2 ubd = __builtin_amdgcn_permlane16_swap(tbd[0], tbd[1], false, false); \
        union { unsigned u[4]; bf16x8 v; } pfu;                                \
        pfu.u[0] = uac[0]; pfu.u[1] = ubd[0];                                  \
        pfu.u[2] = uac[1]; pfu.u[3] = ubd[1];                                  \
        __builtin_amdgcn_s_setprio(1);                                         \
        lsum[ms] = __builtin_amdgcn_mfma_f32_16x16x32_bf16(ones8, pfu.v, lsum[ms], 0, 0, 0); \
        o[ms][0] = __builtin_amdgcn_mfma_f32_16x16x32_bf16(vf[0], pfu.v, o[ms][0], 0, 0, 0); \
        o[ms][1] = __builtin_amdgcn_mfma_f32_16x16x32_bf16(vf[1], pfu.v, o[ms][1], 0, 0, 0); \
        o[ms][2] = __builtin_amdgcn_mfma_f32_16x16x32_bf16(vf[2], pfu.v, o[ms][2], 0, 0, 0); \
        o[ms][3] = __builtin_amdgcn_mfma_f32_16x16x32_bf16(vf[3], pfu.v, o[ms][3], 0, 0, 0); \
        __builtin_amdgcn_s_setprio(0);                                         \
    } while (0)

__global__ __launch_bounds__(512, 4) void attn_k32pv(
    const float* __restrict__ Qg, const float* __restrict__ Kg,
    const float* __restrict__ Vg, float* __restrict__ Og)
{
    __shared__ __align__(16) char smem[SMEM_BYTES];
    _Float16* Kf0 = (_Float16*)smem;
    _Float16* Kf1 = (_Float16*)(smem + 11264);
    __bf16*   Vt0 = (__bf16*)(smem + 22528);
    __bf16*   Vt1 = (__bf16*)(smem + 33792);
    float*    Sc  = (float*)smem;                   // epilogue overlay

    const int tid  = threadIdx.x;
    const int w    = tid >> 6;         // 0..7
    const int qsub = w & 3;
    const int ks   = w >> 2;           // key-half 0/1
    const int ln   = tid & 15;
    const int lg   = (tid >> 4) & 3;

    // XCD-aware bijective swizzle (512 % 8 == 0)
    const int blk   = (blockIdx.x & 7) * 64 + (blockIdx.x >> 3);
    const int qtile = blk & (L_ / QB_ - 1);
    const int bh    = blk >> 4;
    const int h     = bh & (H_ - 1);
    const int b     = bh >> 3;

    const size_t bhbase = (size_t)b * (L_ * H_ * D_) + (size_t)h * D_;
    const int    qbase  = qtile * QB_ + qsub * QW_;

    // ---- Q fragments f16, pre-scaled by log2e ----
    f16x8 qf[2][2];
#pragma unroll
    for (int ms = 0; ms < 2; ++ms) {
#pragma unroll
        for (int dc = 0; dc < 2; ++dc) {
            const float* src = Qg + bhbase
                + (size_t)(qbase + ms * 16 + ln) * RST_ + dc * 32 + lg * 8;
            const float4 a = ((const float4*)src)[0];
            const float4 c = ((const float4*)src)[1];
            f16x8 f;
            f[0] = (_Float16)(a.x * LOG2E_); f[1] = (_Float16)(a.y * LOG2E_);
            f[2] = (_Float16)(a.z * LOG2E_); f[3] = (_Float16)(a.w * LOG2E_);
            f[4] = (_Float16)(c.x * LOG2E_); f[5] = (_Float16)(c.y * LOG2E_);
            f[6] = (_Float16)(c.z * LOG2E_); f[7] = (_Float16)(c.w * LOG2E_);
            qf[ms][dc] = f;
        }
    }

    f32x4 o[2][4];          // O^T partial: lane holds d=dg*16+lg*4+r, q=ln
    f32x4 lsum[2];
#pragma unroll
    for (int ms = 0; ms < 2; ++ms) {
        lsum[ms] = (f32x4){0.f, 0.f, 0.f, 0.f};
#pragma unroll
        for (int dg = 0; dg < 4; ++dg) o[ms][dg] = (f32x4){0.f, 0.f, 0.f, 0.f};
    }

    bf16x8 ones8;
#pragma unroll
    for (int j = 0; j < 8; ++j) ones8[j] = (__bf16)1.0f;

    // ---- staging mappings ----
    const int krow = tid >> 3;            // 0..63
    const int kd8  = (tid & 7) * 8;       // 0..56
    const int vkp  = (tid & 31) * 2;      // key pair base 0..62 (even)
    const int vdb  = (tid >> 5) * 4;      // d base 0..60

    const float* kp = Kg + bhbase + (size_t)krow * RST_ + kd8;
    const float* vp = Vg + bhbase + (size_t)vkp * RST_ + vdb;

    // single stage set: NAMED float4 scalars (spill-proof)
    float4 sk0, sk1, sv0, sv1;

    auto issue = [&]() {
        sk0 = ((const float4*)kp)[0];
        sk1 = ((const float4*)kp)[1];
        sv0 = ((const float4*)vp)[0];
        sv1 = ((const float4*)(vp + RST_))[0];
        kp += (size_t)KT_ * RST_;
        vp += (size_t)KT_ * RST_;
    };
    auto writeKV = [&](_Float16* Kf, __bf16* Vt) {
        f16x8 kw;
        kw[0] = (_Float16)sk0.x; kw[1] = (_Float16)sk0.y;
        kw[2] = (_Float16)sk0.z; kw[3] = (_Float16)sk0.w;
        kw[4] = (_Float16)sk1.x; kw[5] = (_Float16)sk1.y;
        kw[6] = (_Float16)sk1.z; kw[7] = (_Float16)sk1.w;
        *(f16x8*)&Kf[krow * RS_ + kd8] = kw;
        *(unsigned*)&Vt[(vdb + 0) * RS_ + vkp] = pk_bf16(sv0.x, sv1.x);
        *(unsigned*)&Vt[(vdb + 1) * RS_ + vkp] = pk_bf16(sv0.y, sv1.y);
        *(unsigned*)&Vt[(vdb + 2) * RS_ + vkp] = pk_bf16(sv0.z, sv1.z);
        *(unsigned*)&Vt[(vdb + 3) * RS_ + vkp] = pk_bf16(sv0.w, sv1.w);
    };

    f16x8 kfr[2][2];
    bf16x8 vf[4];
    auto readFrags = [&](const _Float16* Kf, const __bf16* Vt) {
#pragma unroll
        for (int dc = 0; dc < 2; ++dc)
#pragma unroll
            for (int kg = 0; kg < 2; ++kg)
                kfr[dc][kg] = *(const f16x8*)
                    &Kf[(ks * 32 + kg * 16 + ln) * RS_ + dc * 32 + lg * 8];
#pragma unroll
        for (int dg = 0; dg < 4; ++dg)
            vf[dg] = *(const bf16x8*)&Vt[(dg * 16 + ln) * RS_ + ks * 32 + lg * 8];
    };

    // ---- prologue: tile0 -> buf0 (serial), tile1 staged in regs ----
    issue();                    // tile 0
    writeKV(Kf0, Vt0);
    issue();                    // tile 1 -> stage regs
    __syncthreads();

    // ---- main loop: ONE barrier/tile, phase-sandwich ordering ----
    for (int t = 0; t < NT_; t += 2) {
        // even tile t from buf0
        readFrags(Kf0, Vt0);
        COMPUTE_MS(0);                      // waits on reads only
        writeKV(Kf1, Vt1);                  // stage tile t+1; drains under MS1
        if (t + 2 < NT_) issue();           // tile t+2 -> stage regs
        COMPUTE_MS(1);                      // register-only MFMAs cover write drain
        __syncthreads();
        // odd tile t+1 from buf1
        readFrags(Kf1, Vt1);
        COMPUTE_MS(0);
        if (t + 2 < NT_) writeKV(Kf0, Vt0); // stage tile t+2
        if (t + 3 < NT_) issue();           // tile t+3 -> stage regs
        COMPUTE_MS(1);
        __syncthreads();
    }

    // ---- merge epilogue (2-way k-split partials add exactly) ----
    const int lane = tid & 63;
    if (w >= 4) {
        float* sc = &Sc[((w - 4) * 64 + lane) * SCW_];
#pragma unroll
        for (int ms = 0; ms < 2; ++ms)
#pragma unroll
            for (int dg = 0; dg < 4; ++dg)
#pragma unroll
                for (int r = 0; r < 4; ++r)
                    sc[ms * 16 + dg * 4 + r] = o[ms][dg][r];
        sc[32] = lsum[0][0];
        sc[33] = lsum[1][0];
    }
    __syncthreads();
    if (w < 4) {
        const float* sc = &Sc[(w * 64 + lane) * SCW_];
        float po[2][4][4];
#pragma unroll
        for (int ms = 0; ms < 2; ++ms)
#pragma unroll
            for (int dg = 0; dg < 4; ++dg)
#pragma unroll
                for (int r = 0; r < 4; ++r)
                    po[ms][dg][r] = o[ms][dg][r] + sc[ms * 16 + dg * 4 + r];
        const float linv[2] = {1.0f / (lsum[0][0] + sc[32]),
                               1.0f / (lsum[1][0] + sc[33])};

        float* Ot = (float*)(smem + w * 8960);    // wave-private, 16B-aligned
        const int qr = lane >> 2;
        const int ch = lane & 3;
#pragma unroll
        for (int ms = 0; ms < 2; ++ms) {
#pragma unroll
            for (int dg = 0; dg < 4; ++dg) {
#pragma unroll
                for (int i = 0; i < 2; ++i) {
                    float2 pr;
                    pr.x = po[ms][dg][2 * i]     * linv[ms];
                    pr.y = po[ms][dg][2 * i + 1] * linv[ms];
                    *(float2*)&Ot[ln * OTS_ + dg * 16 + lg * 4 + 2 * i] = pr;
                }
            }
#pragma unroll
            for (int p = 0; p < 4; ++p) {
                const float4 vo = *(const float4*)&Ot[qr * OTS_ + ch * 4 + p * 16];
                *(float4*)(Og + bhbase
                    + (size_t)(qbase + ms * 16 + qr) * RST_ + ch * 4 + p * 16) = vo;
            }
        }
    }
}

extern "C" void kernel_launch(void* const* d_in, const int* in_sizes, int n_in,
                              void* d_out, int out_size, void* d_ws, size_t ws_size,
                              hipStream_t stream) {
    const float* Q = (const float*)d_in[0];
    const float* K = (const float*)d_in[1];
    const float* V = (const float*)d_in[2];
    float* O = (float*)d_out;

    const int grid = B_ * H_ * (L_ / QB_);   // 512 blocks x 512 threads
    attn_k32pv<<<grid, 512, 0, stream>>>(Q, K, V, O);
}